// Round 3
// baseline (279.767 us; speedup 1.0000x reference)
//
#include <hip/hip_runtime.h>
#include <hip/hip_bf16.h>
#include <cstdint>
#include <cstddef>

typedef __bf16 bf16x8 __attribute__((ext_vector_type(8)));
typedef __bf16 bf16x4 __attribute__((ext_vector_type(4)));
typedef float f32x4 __attribute__((ext_vector_type(4)));

#define BATCH 16
#define MDIM 1024
#define NDIM 4096
#define KDIM 1024
#define BM 128
#define BN 128
#define BK 64
#define NKT (KDIM / BK)  // 16

__device__ __forceinline__ void gload_lds16(const void* g, void* l) {
  __builtin_amdgcn_global_load_lds(
      (const __attribute__((address_space(1))) void*)g,
      (__attribute__((address_space(3))) void*)l, 16, 0, 0);
}

#define BAR() __builtin_amdgcn_s_barrier()
#define SB() __builtin_amdgcn_sched_barrier(0)
#define FENCE() asm volatile("" ::: "memory")
#define LGKM0()                                        \
  do {                                                 \
    asm volatile("s_waitcnt lgkmcnt(0)" ::: "memory"); \
    SB();                                              \
  } while (0)
#define VMC32()                                        \
  do {                                                 \
    asm volatile("s_waitcnt vmcnt(32)" ::: "memory");  \
    SB();                                              \
  } while (0)
#define VMC0()                                         \
  do {                                                 \
    asm volatile("s_waitcnt vmcnt(0)" ::: "memory");   \
    SB();                                              \
  } while (0)

// ---------------------------------------------------------------------------
// Kernel 1: W~[b][o][i] bf16 into workspace (~10us).  (unchanged)
// ---------------------------------------------------------------------------
__global__ __launch_bounds__(256) void modw_kernel(
    const float* __restrict__ weight, const float* __restrict__ y,
    __bf16* __restrict__ wm) {
  const int blk = blockIdx.x;  // 16384
  const int b = blk & 15;
  const int o = blk >> 4;
  const int t = threadIdx.x;
  const float4 w4 = reinterpret_cast<const float4*>(weight + (size_t)o * KDIM)[t];
  const float4 y4 = reinterpret_cast<const float4*>(y + (size_t)b * KDIM)[t];
  const float p0 = w4.x * y4.x, p1 = w4.y * y4.y;
  const float p2 = w4.z * y4.z, p3 = w4.w * y4.w;
  float s = p0 * p0 + p1 * p1 + p2 * p2 + p3 * p3;
#pragma unroll
  for (int off = 32; off >= 1; off >>= 1) s += __shfl_xor(s, off, 64);
  __shared__ float ps[4];
  if ((t & 63) == 0) ps[t >> 6] = s;
  __syncthreads();
  const float tot = ps[0] + ps[1] + ps[2] + ps[3];
  const float scale = 0.03125f;  // 1/sqrt(1024)
  const float dn = scale * rsqrtf(scale * scale * tot + 1e-8f);
  bf16x4 v;
  v[0] = (__bf16)(p0 * dn);
  v[1] = (__bf16)(p1 * dn);
  v[2] = (__bf16)(p2 * dn);
  v[3] = (__bf16)(p3 * dn);
  *reinterpret_cast<bf16x4*>(wm + ((size_t)b * MDIM + o) * KDIM + t * 4) = v;
}

// ---------------------------------------------------------------------------
// Kernel 2: 128x128x64 tiles, 256 threads (4 waves, 2x2), LDS 64 KB ->
// 2 INDEPENDENT blocks per CU.  Rationale: at 1 block/CU both waves on each
// SIMD share every barrier/vmcnt sync point -> 62% issue-idle (R1/R2 evidence:
// schedule shuffles within the lockstep structure are neutral).  Two blocks
// give each SIMD 2 waves with UNCORRELATED sync points, so one block's MFMA
// covers the other's stalls.  All verified machinery preserved: same BK=64
// K-order (bit-identical numerics), same XOR swizzles, same VMEM-queue
// invariant [A-stage(4) older, B-loads(32) younger] -> vmcnt(32).
// ---------------------------------------------------------------------------
__global__ __launch_bounds__(256, 2) void gemm_kernel(
    const __bf16* __restrict__ Wm, const float* __restrict__ E,
    float* __restrict__ out) {
  const int orig = blockIdx.x;  // 4096
  const int wg = (orig & 7) * 512 + (orig >> 3);  // bijective XCD swizzle
  const int mt = wg & 7;          // 8 m-tiles: consecutive wg share E panel
  const int nt = (wg >> 3) & 31;  // 32 n-tiles
  const int b = wg >> 8;
  const int m0 = mt * BM, n0 = nt * BN;

  __shared__ __align__(16) char smem[65536];
  char* const A0_ = smem;
  char* const A1_ = smem + 16384;
  char* const B0_ = smem + 32768;
  char* const B1_ = smem + 49152;

  const int tid = threadIdx.x;  // 256
  const int lane = tid & 63;
  const int wid = tid >> 6;  // 0..3
  const int wr = wid >> 1;   // 0..1  (64 rows each)
  const int wc = wid & 1;    // 0..1  (64 cols each)
  const int ml = lane & 15;
  const int kg = lane >> 4;

  // ---- A staging: 128x64 bf16 = 16 KB/tile, 4 gload_lds rounds ----
  const int arow = tid >> 3;                      // 0..31, +32/round
  const int aswz = ((tid & 7) ^ (arow & 7)) * 8;  // pre-swizzled k-elem off
  const __bf16* Ag = Wm + ((size_t)(b * MDIM + m0 + arow)) * KDIM + aswz;
  const int aldsOff = tid * 16;

  // ---- B staging: 64x128 fp32 loads -> bf16 [128n][64k] LDS ----
  const int bn1 = tid & 63;
  const int bkg = tid >> 6;  // 0..3 (8 k-rows each, x2 k-halves)
  typedef const __attribute__((address_space(1))) float gfloat;
  gfloat* Eg = (gfloat*)(E + (size_t)b * KDIM * NDIM +
                         (size_t)(bkg * 8) * NDIM + n0 + bn1);
  int bwr[4];  // [c*2+h]
#pragma unroll
  for (int c = 0; c < 2; ++c)
#pragma unroll
    for (int h = 0; h < 2; ++h) {
      const int n = bn1 + 64 * c;
      const int kbyte = bkg * 16 + h * 64;
      bwr[c * 2 + h] = n * 128 + (kbyte ^ ((n & 7) << 4));
    }

  // ---- compute-side fragment addressing ----
  const int colA = (kg * 16) ^ ((ml & 7) << 4);
  const int arB = (wr * 64 + ml) * 128;
  const int brB = (wc * 64 + ml) * 128;

  f32x4 acc[4][4];
#pragma unroll
  for (int i = 0; i < 4; ++i)
#pragma unroll
    for (int j = 0; j < 4; ++j) acc[i][j] = (f32x4){0.f, 0.f, 0.f, 0.f};

  auto stageA = [&](char* Ab, int kt) {
#pragma unroll
    for (int r = 0; r < 4; ++r)
      gload_lds16(Ag + (size_t)(32 * r) * KDIM + kt * BK,
                  Ab + aldsOff + r * 4096);
  };
  auto loadB = [&](float (&brr)[4][8], int kt) {
#pragma unroll
    for (int c = 0; c < 2; ++c)
#pragma unroll
      for (int h = 0; h < 2; ++h)
#pragma unroll
        for (int j = 0; j < 8; ++j)
          brr[c * 2 + h][j] =
              Eg[(size_t)(kt * BK + h * 32 + j) * NDIM + 64 * c];
  };
  auto writeB = [&](char* Bb, float (&brr)[4][8]) {
#pragma unroll
    for (int g = 0; g < 4; ++g) {
      bf16x8 v;
#pragma unroll
      for (int j = 0; j < 8; ++j) v[j] = (__bf16)brr[g][j];
      *reinterpret_cast<bf16x8*>(Bb + bwr[g]) = v;
    }
  };

  float br[4][8];  // B reg-stage (32 VGPR), persistent across iterations

  // ---- prologue: A0/B0 <- tile 0 (full drain, once); br <- tile 1 ----
  {
    float brT[4][8];
    stageA(A0_, 0);  // queue [A0(4)]
    FENCE();
    loadB(brT, 0);     // queue [A0(4), brT(32)]
    writeB(B0_, brT);  // auto-wait drains everything (prologue only)
    loadB(br, 1);      // queue [br1(32)]  == loop entry invariant
    LGKM0();
    BAR();
  }

  char* Ac = A0_;
  char* Ao = A1_;
  char* Bc = B0_;
  char* Bo = B1_;

#pragma unroll 1
  for (int t = 0; t < NKT; ++t) {
    // --- head-of-tile staging (R1 ordering): publish t+1, prefetch t+2 ---
    if (t + 1 < NKT) {
      writeB(Bo, br);    // auto vmcnt wait: br (tile t+1, issued 1 tile ago)
      stageA(Ao, t + 1); // 4 gload_lds; must precede loadB in VMEM order
      FENCE();
    }
    if (t + 2 < NKT) loadB(br, t + 2);  // 32 loads, stay in flight

    // --- compute tile t from Ac/Bc ---
#pragma unroll
    for (int kk = 0; kk < 2; ++kk) {
      const int kx = colA ^ (kk * 64);
      bf16x8 af[4], bf[4];
#pragma unroll
      for (int nf = 0; nf < 4; ++nf)
        bf[nf] = *reinterpret_cast<const bf16x8*>(Bc + brB + nf * 2048 + kx);
#pragma unroll
      for (int i = 0; i < 4; ++i)
        af[i] = *reinterpret_cast<const bf16x8*>(Ac + arB + i * 2048 + kx);
      __builtin_amdgcn_s_setprio(1);
#pragma unroll
      for (int i = 0; i < 4; ++i)
#pragma unroll
        for (int nf = 0; nf < 4; ++nf)
          acc[i][nf] = __builtin_amdgcn_mfma_f32_16x16x32_bf16(
              af[i], bf[nf], acc[i][nf], 0, 0, 0);
      __builtin_amdgcn_s_setprio(0);
    }

    // --- single sync point per K-tile ---
    if (t + 2 < NKT) {
      VMC32();  // queue [Ao-stage(4), br(32)] -> drains the A stage only
    } else {
      VMC0();   // tail: no br loads in flight; drain remaining stage
    }
    LGKM0();    // my B ds_writes visible (+ all frag reads done)
    BAR();      // flip: Ao/Bo become current

    char* ta = Ac; Ac = Ao; Ao = ta;
    char* tb = Bc; Bc = Bo; Bo = tb;
  }

  // ---- epilogue ----
  float* ob = out + ((size_t)(b * MDIM + m0 + wr * 64 + kg * 4)) * NDIM +
              n0 + wc * 64 + ml;
#pragma unroll
  for (int mf = 0; mf < 4; ++mf)
#pragma unroll
    for (int nf = 0; nf < 4; ++nf) {
      const f32x4 a = acc[mf][nf];
      float* p = ob + (size_t)mf * 16 * NDIM + nf * 16;
#pragma unroll
      for (int q = 0; q < 4; ++q) p[(size_t)q * NDIM] = a[q];
    }
}

extern "C" void kernel_launch(void* const* d_in, const int* in_sizes, int n_in,
                              void* d_out, int out_size, void* d_ws,
                              size_t ws_size, hipStream_t stream) {
  (void)in_sizes;
  (void)n_in;
  (void)out_size;
  (void)ws_size;
  const float* Efou = (const float*)d_in[0];
  const float* y = (const float*)d_in[1];
  const float* weight = (const float*)d_in[2];
  float* outp = (float*)d_out;
  __bf16* wm = (__bf16*)d_ws;  // 32 MB

  modw_kernel<<<dim3(BATCH * MDIM), dim3(256), 0, stream>>>(weight, y, wm);
  gemm_kernel<<<dim3(BATCH * (MDIM / BM) * (NDIM / BN)), dim3(256), 0,
                stream>>>(wm, Efou, outp);
}

// Round 4
// 273.369 us; speedup vs baseline: 1.0234x; 1.0234x over previous
//
#include <hip/hip_runtime.h>
#include <hip/hip_bf16.h>
#include <cstdint>
#include <cstddef>

typedef __bf16 bf16x8 __attribute__((ext_vector_type(8)));
typedef __bf16 bf16x4 __attribute__((ext_vector_type(4)));
typedef float f32x4 __attribute__((ext_vector_type(4)));

#define BATCH 16
#define MDIM 1024
#define NDIM 4096
#define KDIM 1024
#define BM 256
#define BN 256
#define BK 64
#define NKT (KDIM / BK)  // 16

__device__ __forceinline__ void gload_lds16(const void* g, void* l) {
  __builtin_amdgcn_global_load_lds(
      (const __attribute__((address_space(1))) void*)g,
      (__attribute__((address_space(3))) void*)l, 16, 0, 0);
}

#define BAR() __builtin_amdgcn_s_barrier()
#define SB() __builtin_amdgcn_sched_barrier(0)
#define FENCE() asm volatile("" ::: "memory")
#define LGKM0()                                        \
  do {                                                 \
    asm volatile("s_waitcnt lgkmcnt(0)" ::: "memory"); \
    SB();                                              \
  } while (0)
#define VMC32()                                        \
  do {                                                 \
    asm volatile("s_waitcnt vmcnt(32)" ::: "memory");  \
    SB();                                              \
  } while (0)
#define VMC0()                                         \
  do {                                                 \
    asm volatile("s_waitcnt vmcnt(0)" ::: "memory");   \
    SB();                                              \
  } while (0)

// ---------------------------------------------------------------------------
// Kernel 1: W~[b][o][i] bf16 into workspace (~10us).  (unchanged)
// ---------------------------------------------------------------------------
__global__ __launch_bounds__(256) void modw_kernel(
    const float* __restrict__ weight, const float* __restrict__ y,
    __bf16* __restrict__ wm) {
  const int blk = blockIdx.x;  // 16384
  const int b = blk & 15;
  const int o = blk >> 4;
  const int t = threadIdx.x;
  const float4 w4 = reinterpret_cast<const float4*>(weight + (size_t)o * KDIM)[t];
  const float4 y4 = reinterpret_cast<const float4*>(y + (size_t)b * KDIM)[t];
  const float p0 = w4.x * y4.x, p1 = w4.y * y4.y;
  const float p2 = w4.z * y4.z, p3 = w4.w * y4.w;
  float s = p0 * p0 + p1 * p1 + p2 * p2 + p3 * p3;
#pragma unroll
  for (int off = 32; off >= 1; off >>= 1) s += __shfl_xor(s, off, 64);
  __shared__ float ps[4];
  if ((t & 63) == 0) ps[t >> 6] = s;
  __syncthreads();
  const float tot = ps[0] + ps[1] + ps[2] + ps[3];
  const float scale = 0.03125f;  // 1/sqrt(1024)
  const float dn = scale * rsqrtf(scale * scale * tot + 1e-8f);
  bf16x4 v;
  v[0] = (__bf16)(p0 * dn);
  v[1] = (__bf16)(p1 * dn);
  v[2] = (__bf16)(p2 * dn);
  v[3] = (__bf16)(p3 * dn);
  *reinterpret_cast<bf16x4*>(wm + ((size_t)b * MDIM + o) * KDIM + t * 4) = v;
}

// ---------------------------------------------------------------------------
// Kernel 1b: transpose+convert E fp32 [b][k][n] -> Eb bf16 [b][n][k].
// 64x64 tiles via LDS (pad 65 -> 2-way conflicts only, free).
// Removes the fp32 B-path (loads+cvt+ds_write) from the GEMM inner loop so
// the GEMM can run the verified m201 8-phase structure with BOTH operands
// staged via global_load_lds.
// ---------------------------------------------------------------------------
__global__ __launch_bounds__(256) void transE_kernel(
    const float* __restrict__ E, __bf16* __restrict__ Eb) {
  const int blk = blockIdx.x;      // 16384
  const int ntile = blk & 63;      // N/64
  const int kt = (blk >> 6) & 15;  // K/64
  const int b = blk >> 10;         // 16
  const int t = threadIdx.x;
  __shared__ float tile[64][65];
  const int tn = (t & 15) * 4;  // n within tile (float4)
  const int tk = t >> 4;        // k within tile, +16/round
  const float* src =
      E + ((size_t)(b * KDIM + kt * 64)) * NDIM + ntile * 64;
#pragma unroll
  for (int r = 0; r < 4; ++r) {
    const int k = tk + 16 * r;
    const float4 v =
        *reinterpret_cast<const float4*>(src + (size_t)k * NDIM + tn);
    tile[k][tn + 0] = v.x;
    tile[k][tn + 1] = v.y;
    tile[k][tn + 2] = v.z;
    tile[k][tn + 3] = v.w;
  }
  __syncthreads();
  const int wk = (t & 15) * 4;  // k within tile (bf16x4)
  __bf16* dst = Eb + ((size_t)(b * NDIM + ntile * 64)) * KDIM +
                (size_t)kt * 64 + wk;
#pragma unroll
  for (int r = 0; r < 4; ++r) {
    const int n = (t >> 4) + 16 * r;
    bf16x4 v;
    v[0] = (__bf16)tile[wk + 0][n];
    v[1] = (__bf16)tile[wk + 1][n];
    v[2] = (__bf16)tile[wk + 2][n];
    v[3] = (__bf16)tile[wk + 3][n];
    *reinterpret_cast<bf16x4*>(dst + (size_t)n * KDIM) = v;
  }
}

// ---------------------------------------------------------------------------
// Kernel 2 (primary): 256x256x64, 8 waves (2x4).  Faithful m201 4-phase/K-tile
// schedule, both operands via global_load_lds (pre-swizzled sources):
//   P0: RD bf(kk0)+af(q0,kk0); stage A(t+1);      BAR lgkm0 MFMA16 BAR
//   P1: RD af(q1,kk0);         stage B(t+1);      BAR lgkm0 MFMA16 BAR
//   P2: RD bf(kk1)+af(q0,kk1);                    BAR lgkm0 MFMA16 BAR
//   P3: RD af(q1,kk1);                            BAR lgkm0 MFMA16 VMC0 BAR
// No fp32 loads, no cvt, no ds_write in the loop.  Stage coverage >= 2 phases.
// ---------------------------------------------------------------------------
__global__ __launch_bounds__(512, 2) void gemm_kernel(
    const __bf16* __restrict__ Wm, const __bf16* __restrict__ Ebt,
    float* __restrict__ out) {
  const int orig = blockIdx.x;  // 1024
  const int wg = (orig & 7) * 128 + (orig >> 3);  // bijective XCD swizzle
  const int mt = wg & 3;
  const int nt = (wg >> 2) & 15;
  const int b = wg >> 6;
  const int m0 = mt * BM, n0 = nt * BN;

  __shared__ __align__(16) char smem[131072];
  char* const A0_ = smem;
  char* const A1_ = smem + 32768;
  char* const B0_ = smem + 65536;
  char* const B1_ = smem + 98304;

  const int tid = threadIdx.x;  // 512
  const int lane = tid & 63;
  const int wid = tid >> 6;  // 0..7
  const int wr = wid >> 2;   // 0..1
  const int wc = wid & 3;    // 0..3
  const int ml = lane & 15;
  const int kg = lane >> 4;

  // ---- staging (identical pattern for A and B; pre-swizzled source) ----
  const int srow = tid >> 3;                      // 0..63, +64/round
  const int sswz = ((tid & 7) ^ (srow & 7)) * 8;  // pre-swizzled k-elem off
  const __bf16* Ag = Wm + ((size_t)(b * MDIM + m0 + srow)) * KDIM + sswz;
  const __bf16* Bg = Ebt + ((size_t)(b * NDIM + n0 + srow)) * KDIM + sswz;
  const int sldsOff = tid * 16;

  // ---- compute-side fragment addressing ----
  const int colA = (kg * 16) ^ ((ml & 7) << 4);
  const int arB = (wr * 128 + ml) * 128;
  const int brB = (wc * 64 + ml) * 128;

  f32x4 acc[8][4];
#pragma unroll
  for (int i = 0; i < 8; ++i)
#pragma unroll
    for (int j = 0; j < 4; ++j) acc[i][j] = (f32x4){0.f, 0.f, 0.f, 0.f};

  auto stageA = [&](char* Ab, int kt) {
#pragma unroll
    for (int r = 0; r < 4; ++r)
      gload_lds16(Ag + (size_t)(64 * r) * KDIM + kt * BK,
                  Ab + sldsOff + r * 8192);
  };
  auto stageB = [&](char* Bb, int kt) {
#pragma unroll
    for (int r = 0; r < 4; ++r)
      gload_lds16(Bg + (size_t)(64 * r) * KDIM + kt * BK,
                  Bb + sldsOff + r * 8192);
  };

#define RD_B(Bc, KKv)                                          \
  do {                                                         \
    _Pragma("unroll") for (int nf = 0; nf < 4; ++nf)           \
        bf[nf] = *reinterpret_cast<const bf16x8*>(             \
            (Bc) + brB + nf * 2048 + (colA ^ ((KKv)*64)));     \
  } while (0)
#define RD_A(Ac, QMv, KKv)                                         \
  do {                                                             \
    _Pragma("unroll") for (int i = 0; i < 4; ++i)                  \
        af[i] = *reinterpret_cast<const bf16x8*>(                  \
            (Ac) + arB + ((QMv)*4 + i) * 2048 + (colA ^ ((KKv)*64))); \
  } while (0)
#define MFMA16(QMv)                                                      \
  do {                                                                   \
    __builtin_amdgcn_s_setprio(1);                                       \
    _Pragma("unroll") for (int i = 0; i < 4; ++i)                        \
        _Pragma("unroll") for (int nf = 0; nf < 4; ++nf)                 \
            acc[(QMv)*4 + i][nf] = __builtin_amdgcn_mfma_f32_16x16x32_bf16( \
                af[i], bf[nf], acc[(QMv)*4 + i][nf], 0, 0, 0);           \
    __builtin_amdgcn_s_setprio(0);                                       \
  } while (0)

  // ---- prologue: A0/B0 <- tile 0, full drain once ----
  stageA(A0_, 0);
  stageB(B0_, 0);
  VMC0();
  BAR();

  char* Ac = A0_;
  char* Ao = A1_;
  char* Bc = B0_;
  char* Bo = B1_;

#pragma unroll 1
  for (int t = 0; t < NKT; ++t) {
    bf16x8 af[4], bf[4];
    const bool pf = (t + 1 < NKT);

    // P0
    RD_B(Bc, 0);
    RD_A(Ac, 0, 0);
    if (pf) stageA(Ao, t + 1);
    BAR();
    LGKM0();
    MFMA16(0);
    BAR();
    // P1
    RD_A(Ac, 1, 0);
    if (pf) stageB(Bo, t + 1);
    BAR();
    LGKM0();
    MFMA16(1);
    BAR();
    // P2
    RD_B(Bc, 1);
    RD_A(Ac, 0, 1);
    BAR();
    LGKM0();
    MFMA16(0);
    BAR();
    // P3
    RD_A(Ac, 1, 1);
    BAR();
    LGKM0();
    MFMA16(1);
    VMC0();  // stage(t+1) done (issued >=2 phases ago); queue empty on tail
    BAR();

    char* ta = Ac; Ac = Ao; Ao = ta;
    char* tb = Bc; Bc = Bo; Bo = tb;
  }
#undef RD_B
#undef RD_A
#undef MFMA16

  // ---- epilogue ----
  float* ob = out + ((size_t)(b * MDIM + m0 + wr * 128 + kg * 4)) * NDIM +
              n0 + wc * 64 + ml;
#pragma unroll
  for (int mf = 0; mf < 8; ++mf)
#pragma unroll
    for (int nf = 0; nf < 4; ++nf) {
      const f32x4 a = acc[mf][nf];
      float* p = ob + (size_t)mf * 16 * NDIM + nf * 16;
#pragma unroll
      for (int q = 0; q < 4; ++q) p[(size_t)q * NDIM] = a[q];
    }
}

// ---------------------------------------------------------------------------
// Kernel 2 (fallback, R1 structure): used only if ws_size < 160 MB.
// fp32 B reg-stage path, 1 barrier per K-tile.  Verified at 213 us.
// ---------------------------------------------------------------------------
__global__ __launch_bounds__(512, 2) void gemm_fb_kernel(
    const __bf16* __restrict__ Wm, const float* __restrict__ E,
    float* __restrict__ out) {
  const int orig = blockIdx.x;  // 1024
  const int wg = (orig & 7) * 128 + (orig >> 3);
  const int mt = wg & 3;
  const int nt = (wg >> 2) & 15;
  const int b = wg >> 6;
  const int m0 = mt * BM, n0 = nt * BN;

  __shared__ __align__(16) char smem[131072];
  char* const A0_ = smem;
  char* const A1_ = smem + 32768;
  char* const B0_ = smem + 65536;
  char* const B1_ = smem + 98304;

  const int tid = threadIdx.x;
  const int lane = tid & 63;
  const int wid = tid >> 6;
  const int wr = wid >> 2;
  const int wc = wid & 3;
  const int ml = lane & 15;
  const int kg = lane >> 4;

  const int arow = tid >> 3;
  const int aswz = ((tid & 7) ^ (arow & 7)) * 8;
  const __bf16* Ag = Wm + ((size_t)(b * MDIM + m0 + arow)) * KDIM + aswz;
  const int aldsOff = tid * 16;

  const int bn1 = tid & 63;
  const int bkg = tid >> 6;
  typedef const __attribute__((address_space(1))) float gfloat;
  gfloat* Eg = (gfloat*)(E + (size_t)b * KDIM * NDIM +
                         (size_t)(bkg * 8) * NDIM + n0 + bn1);
  int bwr[4];
#pragma unroll
  for (int c = 0; c < 4; ++c) {
    const int n = bn1 + 64 * c;
    bwr[c] = n * 128 + ((bkg * 16) ^ ((n & 7) << 4));
  }

  const int colA = (kg * 16) ^ ((ml & 7) << 4);
  const int arB = (wr * 128 + ml) * 128;
  const int brB = (wc * 64 + ml) * 128;

  f32x4 acc[8][4];
#pragma unroll
  for (int i = 0; i < 8; ++i)
#pragma unroll
    for (int j = 0; j < 4; ++j) acc[i][j] = (f32x4){0.f, 0.f, 0.f, 0.f};

  auto stageA = [&](char* Ab, int kt) {
#pragma unroll
    for (int r = 0; r < 4; ++r)
      gload_lds16(Ag + (size_t)(64 * r) * KDIM + kt * BK,
                  Ab + aldsOff + r * 8192);
  };
  auto loadB = [&](float (&brr)[4][8], int kt) {
#pragma unroll
    for (int c = 0; c < 4; ++c)
#pragma unroll
      for (int j = 0; j < 8; ++j)
        brr[c][j] = Eg[(size_t)(kt * BK + j) * NDIM + 64 * c];
  };
  auto writeB = [&](char* Bb, float (&brr)[4][8]) {
#pragma unroll
    for (int c = 0; c < 4; ++c) {
      bf16x8 v;
#pragma unroll
      for (int j = 0; j < 8; ++j) v[j] = (__bf16)brr[c][j];
      *reinterpret_cast<bf16x8*>(Bb + bwr[c]) = v;
    }
  };

  float br[4][8];

  {
    float brT[4][8];
    stageA(A0_, 0);
    FENCE();
    loadB(brT, 0);
    writeB(B0_, brT);
    loadB(br, 1);
    LGKM0();
    BAR();
  }

  char* Ac = A0_;
  char* Ao = A1_;
  char* Bc = B0_;
  char* Bo = B1_;

#pragma unroll 1
  for (int t = 0; t < NKT; ++t) {
    if (t + 1 < NKT) {
      writeB(Bo, br);
      stageA(Ao, t + 1);
      FENCE();
    }
    if (t + 2 < NKT) loadB(br, t + 2);

#pragma unroll
    for (int kk = 0; kk < 2; ++kk) {
      const int kx = colA ^ (kk * 64);
      bf16x8 af[4], bf[4];
#pragma unroll
      for (int nf = 0; nf < 4; ++nf)
        bf[nf] = *reinterpret_cast<const bf16x8*>(Bc + brB + nf * 2048 + kx);
#pragma unroll
      for (int i = 0; i < 4; ++i)
        af[i] = *reinterpret_cast<const bf16x8*>(Ac + arB + i * 2048 + kx);
      __builtin_amdgcn_s_setprio(1);
#pragma unroll
      for (int i = 0; i < 4; ++i)
#pragma unroll
        for (int nf = 0; nf < 4; ++nf)
          acc[i][nf] = __builtin_amdgcn_mfma_f32_16x16x32_bf16(
              af[i], bf[nf], acc[i][nf], 0, 0, 0);
      __builtin_amdgcn_s_setprio(0);
#pragma unroll
      for (int i = 0; i < 4; ++i)
        af[i] = *reinterpret_cast<const bf16x8*>(Ac + arB + (4 + i) * 2048 + kx);
      __builtin_amdgcn_s_setprio(1);
#pragma unroll
      for (int i = 0; i < 4; ++i)
#pragma unroll
        for (int nf = 0; nf < 4; ++nf)
          acc[4 + i][nf] = __builtin_amdgcn_mfma_f32_16x16x32_bf16(
              af[i], bf[nf], acc[4 + i][nf], 0, 0, 0);
      __builtin_amdgcn_s_setprio(0);
    }

    if (t + 2 < NKT) {
      VMC32();
    } else {
      VMC0();
    }
    LGKM0();
    BAR();

    char* ta = Ac; Ac = Ao; Ao = ta;
    char* tb = Bc; Bc = Bo; Bo = tb;
  }

  float* ob = out + ((size_t)(b * MDIM + m0 + wr * 128 + kg * 4)) * NDIM +
              n0 + wc * 64 + ml;
#pragma unroll
  for (int mf = 0; mf < 8; ++mf)
#pragma unroll
    for (int nf = 0; nf < 4; ++nf) {
      const f32x4 a = acc[mf][nf];
      float* p = ob + (size_t)mf * 16 * NDIM + nf * 16;
#pragma unroll
      for (int q = 0; q < 4; ++q) p[(size_t)q * NDIM] = a[q];
    }
}

extern "C" void kernel_launch(void* const* d_in, const int* in_sizes, int n_in,
                              void* d_out, int out_size, void* d_ws,
                              size_t ws_size, hipStream_t stream) {
  (void)in_sizes;
  (void)n_in;
  (void)out_size;
  const float* Efou = (const float*)d_in[0];
  const float* y = (const float*)d_in[1];
  const float* weight = (const float*)d_in[2];
  float* outp = (float*)d_out;
  __bf16* wm = (__bf16*)d_ws;  // 32 MB
  const size_t wm_bytes = (size_t)BATCH * MDIM * KDIM * 2;          // 32 MB
  const size_t eb_bytes = (size_t)BATCH * NDIM * KDIM * 2;          // 128 MB

  modw_kernel<<<dim3(BATCH * MDIM), dim3(256), 0, stream>>>(weight, y, wm);

  if (ws_size >= wm_bytes + eb_bytes) {
    __bf16* Eb = (__bf16*)((char*)d_ws + wm_bytes);
    transE_kernel<<<dim3(BATCH * (KDIM / 64) * (NDIM / 64)), dim3(256), 0,
                    stream>>>(Efou, Eb);
    gemm_kernel<<<dim3(BATCH * (MDIM / BM) * (NDIM / BN)), dim3(512), 0,
                  stream>>>(wm, Eb, outp);
  } else {
    gemm_fb_kernel<<<dim3(BATCH * (MDIM / BM) * (NDIM / BN)), dim3(512), 0,
                     stream>>>(wm, Efou, outp);
  }
}

// Round 5
// 272.038 us; speedup vs baseline: 1.0284x; 1.0049x over previous
//
#include <hip/hip_runtime.h>
#include <hip/hip_bf16.h>
#include <cstdint>
#include <cstddef>

typedef __bf16 bf16x8 __attribute__((ext_vector_type(8)));
typedef __bf16 bf16x4 __attribute__((ext_vector_type(4)));
typedef float f32x4 __attribute__((ext_vector_type(4)));

#define BATCH 16
#define MDIM 1024
#define NDIM 4096
#define KDIM 1024
#define BM 256
#define BN 256
#define BK 64
#define NKT (KDIM / BK)  // 16

__device__ __forceinline__ void gload_lds16(const void* g, void* l) {
  __builtin_amdgcn_global_load_lds(
      (const __attribute__((address_space(1))) void*)g,
      (__attribute__((address_space(3))) void*)l, 16, 0, 0);
}

#define BAR() __builtin_amdgcn_s_barrier()
#define SB() __builtin_amdgcn_sched_barrier(0)
#define FENCE() asm volatile("" ::: "memory")
#define LGKM0()                                        \
  do {                                                 \
    asm volatile("s_waitcnt lgkmcnt(0)" ::: "memory"); \
    SB();                                              \
  } while (0)
#define VMC2()                                         \
  do {                                                 \
    asm volatile("s_waitcnt vmcnt(2)" ::: "memory");   \
    SB();                                              \
  } while (0)
#define VMC32()                                        \
  do {                                                 \
    asm volatile("s_waitcnt vmcnt(32)" ::: "memory");  \
    SB();                                              \
  } while (0)
#define VMC0()                                         \
  do {                                                 \
    asm volatile("s_waitcnt vmcnt(0)" ::: "memory");   \
    SB();                                              \
  } while (0)

// ---------------------------------------------------------------------------
// Kernel 1: W~[b][o][i] bf16 into workspace (~10us).  (unchanged)
// ---------------------------------------------------------------------------
__global__ __launch_bounds__(256) void modw_kernel(
    const float* __restrict__ weight, const float* __restrict__ y,
    __bf16* __restrict__ wm) {
  const int blk = blockIdx.x;  // 16384
  const int b = blk & 15;
  const int o = blk >> 4;
  const int t = threadIdx.x;
  const float4 w4 = reinterpret_cast<const float4*>(weight + (size_t)o * KDIM)[t];
  const float4 y4 = reinterpret_cast<const float4*>(y + (size_t)b * KDIM)[t];
  const float p0 = w4.x * y4.x, p1 = w4.y * y4.y;
  const float p2 = w4.z * y4.z, p3 = w4.w * y4.w;
  float s = p0 * p0 + p1 * p1 + p2 * p2 + p3 * p3;
#pragma unroll
  for (int off = 32; off >= 1; off >>= 1) s += __shfl_xor(s, off, 64);
  __shared__ float ps[4];
  if ((t & 63) == 0) ps[t >> 6] = s;
  __syncthreads();
  const float tot = ps[0] + ps[1] + ps[2] + ps[3];
  const float scale = 0.03125f;  // 1/sqrt(1024)
  const float dn = scale * rsqrtf(scale * scale * tot + 1e-8f);
  bf16x4 v;
  v[0] = (__bf16)(p0 * dn);
  v[1] = (__bf16)(p1 * dn);
  v[2] = (__bf16)(p2 * dn);
  v[3] = (__bf16)(p3 * dn);
  *reinterpret_cast<bf16x4*>(wm + ((size_t)b * MDIM + o) * KDIM + t * 4) = v;
}

// ---------------------------------------------------------------------------
// Kernel 1b: transpose+convert E fp32 [b][k][n] -> Eb bf16 [b][n][k].
// (unchanged this round; ~89us measured, tune next round)
// ---------------------------------------------------------------------------
__global__ __launch_bounds__(256) void transE_kernel(
    const float* __restrict__ E, __bf16* __restrict__ Eb) {
  const int blk = blockIdx.x;      // 16384
  const int ntile = blk & 63;      // N/64
  const int kt = (blk >> 6) & 15;  // K/64
  const int b = blk >> 10;         // 16
  const int t = threadIdx.x;
  __shared__ float tile[64][65];
  const int tn = (t & 15) * 4;  // n within tile (float4)
  const int tk = t >> 4;        // k within tile, +16/round
  const float* src =
      E + ((size_t)(b * KDIM + kt * 64)) * NDIM + ntile * 64;
#pragma unroll
  for (int r = 0; r < 4; ++r) {
    const int k = tk + 16 * r;
    const float4 v =
        *reinterpret_cast<const float4*>(src + (size_t)k * NDIM + tn);
    tile[k][tn + 0] = v.x;
    tile[k][tn + 1] = v.y;
    tile[k][tn + 2] = v.z;
    tile[k][tn + 3] = v.w;
  }
  __syncthreads();
  const int wk = (t & 15) * 4;  // k within tile (bf16x4)
  __bf16* dst = Eb + ((size_t)(b * NDIM + ntile * 64)) * KDIM +
                (size_t)kt * 64 + wk;
#pragma unroll
  for (int r = 0; r < 4; ++r) {
    const int n = (t >> 4) + 16 * r;
    bf16x4 v;
    v[0] = (__bf16)tile[wk + 0][n];
    v[1] = (__bf16)tile[wk + 1][n];
    v[2] = (__bf16)tile[wk + 2][n];
    v[3] = (__bf16)tile[wk + 3][n];
    *reinterpret_cast<bf16x4*>(dst + (size_t)n * KDIM) = v;
  }
}

// ---------------------------------------------------------------------------
// Kernel 2 (primary): 256x256x64, 8 waves.  4-phase/K-tile schedule with
// COUNTED boundary vmcnt (T4, m218: counted-vs-drain0 = +38..73%):
//   P0: RD(q0,kk0); stage A(t+1) r1,r3            BAR lgkm0 MFMA16 BAR
//   P1: RD(q1,kk0); stage B(t+1) r0..r3           BAR lgkm0 MFMA16 BAR
//   P2: RD(q0,kk1);                               BAR lgkm0 MFMA16 BAR
//   P3: RD(q1,kk1); deep-stage A(t+2) r0,r2 into  BAR lgkm0 MFMA16 VMC2 BAR
//       the CURRENT buffer (rounds 0,2 last read at P2 -> free after P2's
//       2nd barrier; block-wide safe).  Those 2 loads stay IN FLIGHT across
//       the boundary, covered at the NEXT tile's boundary (4.5 phases).
// Per-thread queue at the boundary wait:
//   [Ar02(t+1)@P3(t-1), Ar13(t+1)@P0, B(t+1)x4@P1, Ar02(t+2)@P3] = 10
//   -> vmcnt(2) drains exactly all of tile t+1.  Tail: vmcnt(0).
// ---------------------------------------------------------------------------
__global__ __launch_bounds__(512, 2) void gemm_kernel(
    const __bf16* __restrict__ Wm, const __bf16* __restrict__ Ebt,
    float* __restrict__ out) {
  const int orig = blockIdx.x;  // 1024
  const int wg = (orig & 7) * 128 + (orig >> 3);  // bijective XCD swizzle
  const int mt = wg & 3;
  const int nt = (wg >> 2) & 15;
  const int b = wg >> 6;
  const int m0 = mt * BM, n0 = nt * BN;

  __shared__ __align__(16) char smem[131072];
  char* const A0_ = smem;
  char* const A1_ = smem + 32768;
  char* const B0_ = smem + 65536;
  char* const B1_ = smem + 98304;

  const int tid = threadIdx.x;  // 512
  const int lane = tid & 63;
  const int wid = tid >> 6;  // 0..7
  const int wr = wid >> 2;   // 0..1
  const int wc = wid & 3;    // 0..3
  const int ml = lane & 15;
  const int kg = lane >> 4;

  // ---- staging (identical pattern for A and B; pre-swizzled source) ----
  const int srow = tid >> 3;                      // 0..63, +64/round
  const int sswz = ((tid & 7) ^ (srow & 7)) * 8;  // pre-swizzled k-elem off
  const __bf16* Ag = Wm + ((size_t)(b * MDIM + m0 + srow)) * KDIM + sswz;
  const __bf16* Bg = Ebt + ((size_t)(b * NDIM + n0 + srow)) * KDIM + sswz;
  const int sldsOff = tid * 16;

  // ---- compute-side fragment addressing ----
  const int colA = (kg * 16) ^ ((ml & 7) << 4);
  const int arB = (wr * 128 + ml) * 128;
  const int brB = (wc * 64 + ml) * 128;

  f32x4 acc[8][4];
#pragma unroll
  for (int i = 0; i < 8; ++i)
#pragma unroll
    for (int j = 0; j < 4; ++j) acc[i][j] = (f32x4){0.f, 0.f, 0.f, 0.f};

  auto stageA = [&](char* Ab, int kt) {  // all 4 rounds (prologue only)
#pragma unroll
    for (int r = 0; r < 4; ++r)
      gload_lds16(Ag + (size_t)(64 * r) * KDIM + kt * BK,
                  Ab + sldsOff + r * 8192);
  };
  auto stageApair = [&](char* Ab, int kt, int ra, int rb) {
    gload_lds16(Ag + (size_t)(64 * ra) * KDIM + kt * BK,
                Ab + sldsOff + ra * 8192);
    gload_lds16(Ag + (size_t)(64 * rb) * KDIM + kt * BK,
                Ab + sldsOff + rb * 8192);
  };
  auto stageB = [&](char* Bb, int kt) {
#pragma unroll
    for (int r = 0; r < 4; ++r)
      gload_lds16(Bg + (size_t)(64 * r) * KDIM + kt * BK,
                  Bb + sldsOff + r * 8192);
  };

#define RD_B(Bc, KKv)                                          \
  do {                                                         \
    _Pragma("unroll") for (int nf = 0; nf < 4; ++nf)           \
        bf[nf] = *reinterpret_cast<const bf16x8*>(             \
            (Bc) + brB + nf * 2048 + (colA ^ ((KKv)*64)));     \
  } while (0)
#define RD_A(Ac, QMv, KKv)                                         \
  do {                                                             \
    _Pragma("unroll") for (int i = 0; i < 4; ++i)                  \
        af[i] = *reinterpret_cast<const bf16x8*>(                  \
            (Ac) + arB + ((QMv)*4 + i) * 2048 + (colA ^ ((KKv)*64))); \
  } while (0)
#define MFMA16(QMv)                                                      \
  do {                                                                   \
    __builtin_amdgcn_s_setprio(1);                                       \
    _Pragma("unroll") for (int i = 0; i < 4; ++i)                        \
        _Pragma("unroll") for (int nf = 0; nf < 4; ++nf)                 \
            acc[(QMv)*4 + i][nf] = __builtin_amdgcn_mfma_f32_16x16x32_bf16( \
                af[i], bf[nf], acc[(QMv)*4 + i][nf], 0, 0, 0);           \
    __builtin_amdgcn_s_setprio(0);                                       \
  } while (0)

  // ---- prologue: tile 0 fully; deep-stage A(t1) r0,r2 (stays in flight) ----
  stageA(A0_, 0);
  stageB(B0_, 0);
  stageApair(A1_, 1, 0, 2);
  VMC2();  // drains tile0's 8 loads; Ar02(t1) in flight
  BAR();

  char* Ac = A0_;
  char* Ao = A1_;
  char* Bc = B0_;
  char* Bo = B1_;

#pragma unroll 1
  for (int t = 0; t < NKT; ++t) {
    bf16x8 af[4], bf[4];
    const bool pf1 = (t + 1 < NKT);
    const bool pf2 = (t + 2 < NKT);

    // P0: q0,kk0 ; stage A(t+1) rounds 1,3 (other buffer, fully free)
    RD_B(Bc, 0);
    RD_A(Ac, 0, 0);
    if (pf1) stageApair(Ao, t + 1, 1, 3);
    BAR();
    LGKM0();
    MFMA16(0);
    BAR();
    // P1: q1,kk0 ; stage B(t+1)
    RD_A(Ac, 1, 0);
    if (pf1) stageB(Bo, t + 1);
    BAR();
    LGKM0();
    MFMA16(1);
    BAR();
    // P2: q0,kk1  (last read of A rounds 0,2 of current buffer)
    RD_B(Bc, 1);
    RD_A(Ac, 0, 1);
    BAR();
    LGKM0();
    MFMA16(0);
    BAR();
    // P3: q1,kk1 ; deep-stage A(t+2) r0,r2 into CURRENT buffer (disjoint
    // from this phase's reads: rounds 1,3).  Safe: r0,r2 free since P2's
    // second barrier, block-wide.
    RD_A(Ac, 1, 1);
    if (pf2) stageApair(Ac, t + 2, 0, 2);
    BAR();
    LGKM0();
    MFMA16(1);
    if (pf2) {
      VMC2();  // drains all tile-(t+1) stages; Ar02(t+2) stays in flight
    } else {
      VMC0();  // tail: drain everything
    }
    BAR();

    char* ta = Ac; Ac = Ao; Ao = ta;
    char* tb = Bc; Bc = Bo; Bo = tb;
  }
#undef RD_B
#undef RD_A
#undef MFMA16

  // ---- epilogue ----
  float* ob = out + ((size_t)(b * MDIM + m0 + wr * 128 + kg * 4)) * NDIM +
              n0 + wc * 64 + ml;
#pragma unroll
  for (int mf = 0; mf < 8; ++mf)
#pragma unroll
    for (int nf = 0; nf < 4; ++nf) {
      const f32x4 a = acc[mf][nf];
      float* p = ob + (size_t)mf * 16 * NDIM + nf * 16;
#pragma unroll
      for (int q = 0; q < 4; ++q) p[(size_t)q * NDIM] = a[q];
    }
}

// ---------------------------------------------------------------------------
// Kernel 2 (fallback, R1 structure): used only if ws_size < 160 MB.
// ---------------------------------------------------------------------------
__global__ __launch_bounds__(512, 2) void gemm_fb_kernel(
    const __bf16* __restrict__ Wm, const float* __restrict__ E,
    float* __restrict__ out) {
  const int orig = blockIdx.x;  // 1024
  const int wg = (orig & 7) * 128 + (orig >> 3);
  const int mt = wg & 3;
  const int nt = (wg >> 2) & 15;
  const int b = wg >> 6;
  const int m0 = mt * BM, n0 = nt * BN;

  __shared__ __align__(16) char smem[131072];
  char* const A0_ = smem;
  char* const A1_ = smem + 32768;
  char* const B0_ = smem + 65536;
  char* const B1_ = smem + 98304;

  const int tid = threadIdx.x;
  const int lane = tid & 63;
  const int wid = tid >> 6;
  const int wr = wid >> 2;
  const int wc = wid & 3;
  const int ml = lane & 15;
  const int kg = lane >> 4;

  const int arow = tid >> 3;
  const int aswz = ((tid & 7) ^ (arow & 7)) * 8;
  const __bf16* Ag = Wm + ((size_t)(b * MDIM + m0 + arow)) * KDIM + aswz;
  const int aldsOff = tid * 16;

  const int bn1 = tid & 63;
  const int bkg = tid >> 6;
  typedef const __attribute__((address_space(1))) float gfloat;
  gfloat* Eg = (gfloat*)(E + (size_t)b * KDIM * NDIM +
                         (size_t)(bkg * 8) * NDIM + n0 + bn1);
  int bwr[4];
#pragma unroll
  for (int c = 0; c < 4; ++c) {
    const int n = bn1 + 64 * c;
    bwr[c] = n * 128 + ((bkg * 16) ^ ((n & 7) << 4));
  }

  const int colA = (kg * 16) ^ ((ml & 7) << 4);
  const int arB = (wr * 128 + ml) * 128;
  const int brB = (wc * 64 + ml) * 128;

  f32x4 acc[8][4];
#pragma unroll
  for (int i = 0; i < 8; ++i)
#pragma unroll
    for (int j = 0; j < 4; ++j) acc[i][j] = (f32x4){0.f, 0.f, 0.f, 0.f};

  auto stageA = [&](char* Ab, int kt) {
#pragma unroll
    for (int r = 0; r < 4; ++r)
      gload_lds16(Ag + (size_t)(64 * r) * KDIM + kt * BK,
                  Ab + aldsOff + r * 8192);
  };
  auto loadB = [&](float (&brr)[4][8], int kt) {
#pragma unroll
    for (int c = 0; c < 4; ++c)
#pragma unroll
      for (int j = 0; j < 8; ++j)
        brr[c][j] = Eg[(size_t)(kt * BK + j) * NDIM + 64 * c];
  };
  auto writeB = [&](char* Bb, float (&brr)[4][8]) {
#pragma unroll
    for (int c = 0; c < 4; ++c) {
      bf16x8 v;
#pragma unroll
      for (int j = 0; j < 8; ++j) v[j] = (__bf16)brr[c][j];
      *reinterpret_cast<bf16x8*>(Bb + bwr[c]) = v;
    }
  };

  float br[4][8];

  {
    float brT[4][8];
    stageA(A0_, 0);
    FENCE();
    loadB(brT, 0);
    writeB(B0_, brT);
    loadB(br, 1);
    LGKM0();
    BAR();
  }

  char* Ac = A0_;
  char* Ao = A1_;
  char* Bc = B0_;
  char* Bo = B1_;

#pragma unroll 1
  for (int t = 0; t < NKT; ++t) {
    if (t + 1 < NKT) {
      writeB(Bo, br);
      stageA(Ao, t + 1);
      FENCE();
    }
    if (t + 2 < NKT) loadB(br, t + 2);

#pragma unroll
    for (int kk = 0; kk < 2; ++kk) {
      const int kx = colA ^ (kk * 64);
      bf16x8 af[4], bf[4];
#pragma unroll
      for (int nf = 0; nf < 4; ++nf)
        bf[nf] = *reinterpret_cast<const bf16x8*>(Bc + brB + nf * 2048 + kx);
#pragma unroll
      for (int i = 0; i < 4; ++i)
        af[i] = *reinterpret_cast<const bf16x8*>(Ac + arB + i * 2048 + kx);
      __builtin_amdgcn_s_setprio(1);
#pragma unroll
      for (int i = 0; i < 4; ++i)
#pragma unroll
        for (int nf = 0; nf < 4; ++nf)
          acc[i][nf] = __builtin_amdgcn_mfma_f32_16x16x32_bf16(
              af[i], bf[nf], acc[i][nf], 0, 0, 0);
      __builtin_amdgcn_s_setprio(0);
#pragma unroll
      for (int i = 0; i < 4; ++i)
        af[i] = *reinterpret_cast<const bf16x8*>(Ac + arB + (4 + i) * 2048 + kx);
      __builtin_amdgcn_s_setprio(1);
#pragma unroll
      for (int i = 0; i < 4; ++i)
#pragma unroll
        for (int nf = 0; nf < 4; ++nf)
          acc[4 + i][nf] = __builtin_amdgcn_mfma_f32_16x16x32_bf16(
              af[i], bf[nf], acc[4 + i][nf], 0, 0, 0);
      __builtin_amdgcn_s_setprio(0);
    }

    if (t + 2 < NKT) {
      VMC32();
    } else {
      VMC0();
    }
    LGKM0();
    BAR();

    char* ta = Ac; Ac = Ao; Ao = ta;
    char* tb = Bc; Bc = Bo; Bo = tb;
  }

  float* ob = out + ((size_t)(b * MDIM + m0 + wr * 128 + kg * 4)) * NDIM +
              n0 + wc * 64 + ml;
#pragma unroll
  for (int mf = 0; mf < 8; ++mf)
#pragma unroll
    for (int nf = 0; nf < 4; ++nf) {
      const f32x4 a = acc[mf][nf];
      float* p = ob + (size_t)mf * 16 * NDIM + nf * 16;
#pragma unroll
      for (int q = 0; q < 4; ++q) p[(size_t)q * NDIM] = a[q];
    }
}

extern "C" void kernel_launch(void* const* d_in, const int* in_sizes, int n_in,
                              void* d_out, int out_size, void* d_ws,
                              size_t ws_size, hipStream_t stream) {
  (void)in_sizes;
  (void)n_in;
  (void)out_size;
  const float* Efou = (const float*)d_in[0];
  const float* y = (const float*)d_in[1];
  const float* weight = (const float*)d_in[2];
  float* outp = (float*)d_out;
  __bf16* wm = (__bf16*)d_ws;  // 32 MB
  const size_t wm_bytes = (size_t)BATCH * MDIM * KDIM * 2;  // 32 MB
  const size_t eb_bytes = (size_t)BATCH * NDIM * KDIM * 2;  // 128 MB

  modw_kernel<<<dim3(BATCH * MDIM), dim3(256), 0, stream>>>(weight, y, wm);

  if (ws_size >= wm_bytes + eb_bytes) {
    __bf16* Eb = (__bf16*)((char*)d_ws + wm_bytes);
    transE_kernel<<<dim3(BATCH * (KDIM / 64) * (NDIM / 64)), dim3(256), 0,
                    stream>>>(Efou, Eb);
    gemm_kernel<<<dim3(BATCH * (MDIM / BM) * (NDIM / BN)), dim3(512), 0,
                  stream>>>(wm, Eb, outp);
  } else {
    gemm_fb_kernel<<<dim3(BATCH * (MDIM / BM) * (NDIM / BN)), dim3(512), 0,
                     stream>>>(wm, Efou, outp);
  }
}

// Round 6
// 211.509 us; speedup vs baseline: 1.3227x; 1.2862x over previous
//
#include <hip/hip_runtime.h>
#include <hip/hip_bf16.h>
#include <cstdint>
#include <cstddef>

typedef __bf16 bf16x8 __attribute__((ext_vector_type(8)));
typedef __bf16 bf16x4 __attribute__((ext_vector_type(4)));
typedef float f32x4 __attribute__((ext_vector_type(4)));

#define BATCH 16
#define MDIM 1024
#define NDIM 4096
#define KDIM 1024
#define BM 256
#define BN 256
#define BK 64
#define NKT (KDIM / BK)  // 16

__device__ __forceinline__ void gload_lds16(const void* g, void* l) {
  __builtin_amdgcn_global_load_lds(
      (const __attribute__((address_space(1))) void*)g,
      (__attribute__((address_space(3))) void*)l, 16, 0, 0);
}

#define BAR() __builtin_amdgcn_s_barrier()
#define SB() __builtin_amdgcn_sched_barrier(0)
#define FENCE() asm volatile("" ::: "memory")
#define LGKM0()                                        \
  do {                                                 \
    asm volatile("s_waitcnt lgkmcnt(0)" ::: "memory"); \
    SB();                                              \
  } while (0)
#define VMC32()                                        \
  do {                                                 \
    asm volatile("s_waitcnt vmcnt(32)" ::: "memory");  \
    SB();                                              \
  } while (0)
#define VMC0()                                         \
  do {                                                 \
    asm volatile("s_waitcnt vmcnt(0)" ::: "memory");   \
    SB();                                              \
  } while (0)

// ---------------------------------------------------------------------------
// Kernel 1: W~[b][o][i] bf16 into workspace (~10us).  (unchanged)
// ---------------------------------------------------------------------------
__global__ __launch_bounds__(256) void modw_kernel(
    const float* __restrict__ weight, const float* __restrict__ y,
    __bf16* __restrict__ wm) {
  const int blk = blockIdx.x;  // 16384
  const int b = blk & 15;
  const int o = blk >> 4;
  const int t = threadIdx.x;
  const float4 w4 = reinterpret_cast<const float4*>(weight + (size_t)o * KDIM)[t];
  const float4 y4 = reinterpret_cast<const float4*>(y + (size_t)b * KDIM)[t];
  const float p0 = w4.x * y4.x, p1 = w4.y * y4.y;
  const float p2 = w4.z * y4.z, p3 = w4.w * y4.w;
  float s = p0 * p0 + p1 * p1 + p2 * p2 + p3 * p3;
#pragma unroll
  for (int off = 32; off >= 1; off >>= 1) s += __shfl_xor(s, off, 64);
  __shared__ float ps[4];
  if ((t & 63) == 0) ps[t >> 6] = s;
  __syncthreads();
  const float tot = ps[0] + ps[1] + ps[2] + ps[3];
  const float scale = 0.03125f;  // 1/sqrt(1024)
  const float dn = scale * rsqrtf(scale * scale * tot + 1e-8f);
  bf16x4 v;
  v[0] = (__bf16)(p0 * dn);
  v[1] = (__bf16)(p1 * dn);
  v[2] = (__bf16)(p2 * dn);
  v[3] = (__bf16)(p3 * dn);
  *reinterpret_cast<bf16x4*>(wm + ((size_t)b * MDIM + o) * KDIM + t * 4) = v;
}

// ---------------------------------------------------------------------------
// Kernel 2: fused 256x256x64, 8 waves, ONE sync point per K-tile, with
// ONE-REGION FRAGMENT READ-AHEAD (the m201 overlap mechanism):
// each region issues the ds_reads for the NEXT region's MFMA, then runs the
// current region's MFMA on previously-read frags.  The LDS unit services the
// reads while the MFMA pipe issues -> no per-phase LDS round-trip stall.
// Frag slots ROTATE (no extra VGPRs): each slot's last use is one region
// before its refill.  Regions per tile t (steady state):
//   R0: rd af1<-(q1,k0);  writeB(Bo,br[t+1]);        MFMA(af0,bf0 ->acc q0)
//   R1: rd bf1<-(k1), af0<-(q0,k1); stageA(Ao,t+1);
//       loadB(br,t+2);                               MFMA(af1,bf0 ->acc q1)
//   R2: rd af1<-(q1,k1);                             MFMA(af0,bf1 ->acc q0)
//       LGKM0 ; VMC32 (tail: VMC0) ; BAR
//   R3: rd af0<-Ao(q0,k0), bf0<-Bo(k0)  [tile t+1];  MFMA(af1,bf1 ->acc q1)
// VMEM queue invariant at the counted wait: [stageA(4) older, br(32) younger]
// -> vmcnt(32) drains exactly the A-stage.  R5 tail bug fixed: when
// t+2>=NKT no br loads are in flight -> VMC0 so stage(t+1) is drained.
// Numerics: same MFMA order as R1 (q0k0,q1k0,q0k1,q1k1) -> bit-identical.
// ---------------------------------------------------------------------------
__global__ __launch_bounds__(512, 2) void gemm_kernel(
    const __bf16* __restrict__ Wm, const float* __restrict__ E,
    float* __restrict__ out) {
  const int orig = blockIdx.x;  // 1024
  const int wg = (orig & 7) * 128 + (orig >> 3);  // bijective XCD swizzle
  const int mt = wg & 3;
  const int nt = (wg >> 2) & 15;
  const int b = wg >> 6;
  const int m0 = mt * BM, n0 = nt * BN;

  __shared__ __align__(16) char smem[131072];
  char* const A0_ = smem;
  char* const A1_ = smem + 32768;
  char* const B0_ = smem + 65536;
  char* const B1_ = smem + 98304;

  const int tid = threadIdx.x;  // 512
  const int lane = tid & 63;
  const int wid = tid >> 6;  // 0..7
  const int wr = wid >> 2;   // 0..1
  const int wc = wid & 3;    // 0..3
  const int ml = lane & 15;
  const int kg = lane >> 4;

  // ---- A staging ----
  const int arow = tid >> 3;                      // 0..63, +64/round
  const int aswz = ((tid & 7) ^ (arow & 7)) * 8;  // pre-swizzled k-elem off
  const __bf16* Ag = Wm + ((size_t)(b * MDIM + m0 + arow)) * KDIM + aswz;
  const int aldsOff = tid * 16;

  // ---- B staging ----
  const int bn1 = tid & 63;
  const int bkg = tid >> 6;
  typedef const __attribute__((address_space(1))) float gfloat;
  gfloat* Eg = (gfloat*)(E + (size_t)b * KDIM * NDIM +
                         (size_t)(bkg * 8) * NDIM + n0 + bn1);
  int bwr[4];
#pragma unroll
  for (int c = 0; c < 4; ++c) {
    const int n = bn1 + 64 * c;
    bwr[c] = n * 128 + ((bkg * 16) ^ ((n & 7) << 4));
  }

  // ---- compute-side fragment addressing ----
  const int colA = (kg * 16) ^ ((ml & 7) << 4);
  const int arB = (wr * 128 + ml) * 128;
  const int brB = (wc * 64 + ml) * 128;

  f32x4 acc[8][4];
#pragma unroll
  for (int i = 0; i < 8; ++i)
#pragma unroll
    for (int j = 0; j < 4; ++j) acc[i][j] = (f32x4){0.f, 0.f, 0.f, 0.f};

  auto stageA = [&](char* Ab, int kt) {
#pragma unroll
    for (int r = 0; r < 4; ++r)
      gload_lds16(Ag + (size_t)(64 * r) * KDIM + kt * BK,
                  Ab + aldsOff + r * 8192);
  };
  auto loadB = [&](float (&brr)[4][8], int kt) {
#pragma unroll
    for (int c = 0; c < 4; ++c)
#pragma unroll
      for (int j = 0; j < 8; ++j)
        brr[c][j] = Eg[(size_t)(kt * BK + j) * NDIM + 64 * c];
  };
  auto writeB = [&](char* Bb, float (&brr)[4][8]) {
#pragma unroll
    for (int c = 0; c < 4; ++c) {
      bf16x8 v;
#pragma unroll
      for (int j = 0; j < 8; ++j) v[j] = (__bf16)brr[c][j];
      *reinterpret_cast<bf16x8*>(Bb + bwr[c]) = v;
    }
  };
  auto rdA = [&](bf16x8 (&d)[4], const char* Ab, int qm, int kk) {
#pragma unroll
    for (int i = 0; i < 4; ++i)
      d[i] = *reinterpret_cast<const bf16x8*>(Ab + arB + (qm * 4 + i) * 2048 +
                                              (colA ^ (kk * 64)));
  };
  auto rdB = [&](bf16x8 (&d)[4], const char* Bb, int kk) {
#pragma unroll
    for (int nf = 0; nf < 4; ++nf)
      d[nf] = *reinterpret_cast<const bf16x8*>(Bb + brB + nf * 2048 +
                                               (colA ^ (kk * 64)));
  };
  auto mfma16 = [&](bf16x8 (&a)[4], bf16x8 (&bv)[4], int qm) {
    __builtin_amdgcn_s_setprio(1);
#pragma unroll
    for (int i = 0; i < 4; ++i)
#pragma unroll
      for (int nf = 0; nf < 4; ++nf)
        acc[qm * 4 + i][nf] = __builtin_amdgcn_mfma_f32_16x16x32_bf16(
            a[i], bv[nf], acc[qm * 4 + i][nf], 0, 0, 0);
    __builtin_amdgcn_s_setprio(0);
  };

  float br[4][8];          // B reg-stage, persistent
  bf16x8 af0[4], af1[4];   // rotating frag slots (q0 / q1 roles)
  bf16x8 bf0[4], bf1[4];   // rotating frag slots (kk0 / kk1 roles)

  // ---- prologue: tile0 into A0/B0 (full drain once); br <- tile1;
  //      pre-read P0 frags of tile0 (left in flight) ----
  {
    float brT[4][8];
    stageA(A0_, 0);  // queue [A0(4)]
    FENCE();
    loadB(brT, 0);     // queue [A0(4), brT(32)]
    writeB(B0_, brT);  // auto vmcnt(0): stage+loads drained
    loadB(br, 1);      // queue [br1(32)]  == loop-entry invariant
    LGKM0();           // ds_writes drained
    BAR();
    rdA(af0, A0_, 0, 0);  // read-ahead for t=0 R0 (compiler-counted wait)
    rdB(bf0, B0_, 0);
  }

  char* Ac = A0_;
  char* Ao = A1_;
  char* Bc = B0_;
  char* Bo = B1_;

#pragma unroll 1
  for (int t = 0; t < NKT; ++t) {
    const bool pf1 = (t + 1 < NKT);
    const bool pf2 = (t + 2 < NKT);

    // R0: read-ahead (q1,k0); publish B(t+1); MFMA q0k0
    rdA(af1, Ac, 1, 0);
    if (pf1) writeB(Bo, br);  // cvt auto-drains br (issued 3 regions ago)
    mfma16(af0, bf0, 0);

    // R1: read-ahead (k1) + (q0,k1); stage A(t+1); prefetch br(t+2); MFMA q1k0
    rdB(bf1, Bc, 1);
    rdA(af0, Ac, 0, 1);
    if (pf1) stageA(Ao, t + 1);
    FENCE();  // pins VMEM order: stage older than br loads
    if (pf2) loadB(br, t + 2);
    mfma16(af1, bf0, 1);

    // R2: read-ahead (q1,k1); MFMA q0k1; single sync point
    rdA(af1, Ac, 1, 1);
    mfma16(af0, bf1, 0);
    LGKM0();  // my frag reads done + my B ds_writes visible-ready
    if (pf2) {
      VMC32();  // queue [stageA(t+1) 4, br(t+2) 32] -> drains the A stage
    } else {
      VMC0();   // tail: no br in flight; drain remaining stage
    }
    BAR();

    // R3: read-ahead tile t+1 P0 frags from Ao/Bo; MFMA q1k1
    if (pf1) {
      rdA(af0, Ao, 0, 0);
      rdB(bf0, Bo, 0);
    }
    mfma16(af1, bf1, 1);

    char* ta = Ac; Ac = Ao; Ao = ta;
    char* tb = Bc; Bc = Bo; Bo = tb;
  }

  // ---- epilogue (unchanged) ----
  float* ob = out + ((size_t)(b * MDIM + m0 + wr * 128 + kg * 4)) * NDIM +
              n0 + wc * 64 + ml;
#pragma unroll
  for (int mf = 0; mf < 8; ++mf)
#pragma unroll
    for (int nf = 0; nf < 4; ++nf) {
      const f32x4 a = acc[mf][nf];
      float* p = ob + (size_t)mf * 16 * NDIM + nf * 16;
#pragma unroll
      for (int q = 0; q < 4; ++q) p[(size_t)q * NDIM] = a[q];
    }
}

extern "C" void kernel_launch(void* const* d_in, const int* in_sizes, int n_in,
                              void* d_out, int out_size, void* d_ws,
                              size_t ws_size, hipStream_t stream) {
  (void)in_sizes;
  (void)n_in;
  (void)out_size;
  (void)ws_size;
  const float* Efou = (const float*)d_in[0];
  const float* y = (const float*)d_in[1];
  const float* weight = (const float*)d_in[2];
  float* outp = (float*)d_out;
  __bf16* wm = (__bf16*)d_ws;  // 32 MB

  modw_kernel<<<dim3(BATCH * MDIM), dim3(256), 0, stream>>>(weight, y, wm);
  gemm_kernel<<<dim3(BATCH * (MDIM / BM) * (NDIM / BN)), dim3(512), 0,
                stream>>>(wm, Efou, outp);
}